// Round 9
// baseline (7520.258 us; speedup 1.0000x reference)
//
#include <hip/hip_runtime.h>
#include <math.h>

// ---------------------------------------------------------------------------
// PointerNetwork: biLSTM encoder + sequential pointer decoder (all fp32).
// Round-7 structure (proven correct): two 256-block mega-dispatches, all
// cross-block exchange at the L3 coherence point (sc0 sc1).
//  phase1: blk 0-63 encoder chains | 192 persistent workers: xWf/xWb
//          (uncached + per-band tile COUNTERS), b12x=x@W2, b3=x@W3 (cached).
//  phase2: blk 0-31 decoder | blk 32-47 fused decide | 208 workers: decIn
//          (uncached + counters) then b12f = b12x + [hn,hb]@W1 (+doneCtr).
// h-exchange rings: 0xAA data-as-flag sentinel polling (the successful poll
// load IS the data load). xW buffers: flag-counter gated (no 192MB poison).
// LSTM step: double-buffered hbuf -> ONE barrier per step.
// NOTE: float4 ok as asm OUTPUT ("=&v"), NOT as input.
// ---------------------------------------------------------------------------

#define SENTU 0xAAAAAAAAu

__device__ __forceinline__ float sigf(float x) { return 1.0f / (1.0f + expf(-x)); }

// ---------------- 64x128 GEMM tile, 512 threads -----------------------------
template<int SRC>
__device__ void gemm_tile(const float* __restrict__ A, const float* __restrict__ A2,
                          const float* __restrict__ B, const float* __restrict__ bias,
                          float* __restrict__ C, int N, int K,
                          int m0, int n0_base, int accum, int uncached,
                          float* __restrict__ smem)
{
  float* As = smem;                 // [16][68]
  float* Bs = smem + 16 * 68;       // [2][16][64]
  const int tid  = threadIdx.x;
  const int half = tid >> 8;
  const int htid = tid & 255;
  const int n0 = n0_base + half * 64;
  float* Bsh = Bs + half * (16 * 64);
  const int am = htid >> 2, akq = htid & 3;
  const int bkk = htid >> 4, bnq = htid & 15;
  const int tx = htid & 15, ty = htid >> 4;
  float acc[4][4] = {};
  for (int k0 = 0; k0 < K; k0 += 16) {
    const int ak = k0 + 4 * akq;
    if (half == 0) {
      const int ar = m0 + am;
      float4 av;
      if (SRC == 0) {
        av = *(const float4*)&A[(size_t)ar * K + ak];
      } else if (SRC == 1) {
        const int bb = ar >> 10, t = ar & 1023;
        if (t == 0) { av = make_float4(0.f, 0.f, 0.f, 0.f); }
        else {
          const int src = ((bb << 10) + (t - 1)) * 256;
          av = (ak < 256) ? *(const float4*)&A[src + ak]
                          : *(const float4*)&A2[src + (ak - 256)];
        }
      } else {
        const int src = ar * 256;
        av = (ak < 256) ? *(const float4*)&A[src + ak]
                        : *(const float4*)&A2[src + (ak - 256)];
      }
      As[(4 * akq + 0) * 68 + am] = av.x;
      As[(4 * akq + 1) * 68 + am] = av.y;
      As[(4 * akq + 2) * 68 + am] = av.z;
      As[(4 * akq + 3) * 68 + am] = av.w;
    }
    const float4 bv = *(const float4*)&B[(size_t)(k0 + bkk) * N + n0 + 4 * bnq];
    *(float4*)&Bsh[bkk * 64 + 4 * bnq] = bv;
    __syncthreads();
#pragma unroll
    for (int kk = 0; kk < 16; ++kk) {
      const float4 a = *(const float4*)&As[kk * 68 + 4 * ty];
      const float4 b = *(const float4*)&Bsh[kk * 64 + 4 * tx];
      acc[0][0] += a.x * b.x; acc[0][1] += a.x * b.y; acc[0][2] += a.x * b.z; acc[0][3] += a.x * b.w;
      acc[1][0] += a.y * b.x; acc[1][1] += a.y * b.y; acc[1][2] += a.y * b.z; acc[1][3] += a.y * b.w;
      acc[2][0] += a.z * b.x; acc[2][1] += a.z * b.y; acc[2][2] += a.z * b.z; acc[2][3] += a.z * b.w;
      acc[3][0] += a.w * b.x; acc[3][1] += a.w * b.y; acc[3][2] += a.w * b.z; acc[3][3] += a.w * b.w;
    }
    __syncthreads();
  }
  const float4 bsv = bias ? *(const float4*)&bias[n0 + 4 * tx] : make_float4(0.f, 0.f, 0.f, 0.f);
#pragma unroll
  for (int i = 0; i < 4; ++i) {
    float* crow = &C[(size_t)(m0 + 4 * ty + i) * N + n0 + 4 * tx];
    float4 old = accum ? *(const float4*)crow : make_float4(0.f, 0.f, 0.f, 0.f);
    float4 r;
    r.x = acc[i][0] + old.x + bsv.x;
    r.y = acc[i][1] + old.y + bsv.y;
    r.z = acc[i][2] + old.z + bsv.z;
    r.w = acc[i][3] + old.w + bsv.w;
    if (uncached) {
      asm volatile("global_store_dword %0, %1, off sc0 sc1"
                   :: "v"(crow), "v"(r.x) : "memory");
      asm volatile("global_store_dword %0, %1, off offset:4 sc0 sc1"
                   :: "v"(crow), "v"(r.y) : "memory");
      asm volatile("global_store_dword %0, %1, off offset:8 sc0 sc1"
                   :: "v"(crow), "v"(r.z) : "memory");
      asm volatile("global_store_dword %0, %1, off offset:12 sc0 sc1"
                   :: "v"(crow), "v"(r.w) : "memory");
    } else {
      *(float4*)crow = r;
    }
  }
}

// ---------------- Sequential LSTM role --------------------------------------
// 512 threads. Compute role tid = cg*64+bg*8+kc; output role tid = sc*16+b.
// xW readiness: per-(band,strip) counters polled once per 64 steps.
// h exchange: never-reused ring, 0xAA data-as-flag sentinel (sc0 sc1).
// hbuf double-buffered -> single __syncthreads per step.
__device__ void lstm_role(const float* __restrict__ xW, const float* __restrict__ Wr,
                          float* __restrict__ hout, const float* __restrict__ cinit,
                          float* __restrict__ rg, const unsigned* __restrict__ xcnt,
                          int g, int rev, float* __restrict__ smem)
{
  float* hbufs = smem;                  // [2][16*260] double buffer
  float* pbuf  = smem + 2 * 16 * 260;   // partials (wave-private)

  const int tid = threadIdx.x;
  const int kc = tid & 7;
  const int bg = (tid >> 3) & 7;
  const int cg = tid >> 6;            // wave id
  const int b    = tid & 15;
  const int sc   = tid >> 4;
  const int gate = sc & 3;
  const int uu   = sc >> 2;           // == wave id for gate0 lanes
  const int u    = g * 8 + uu;
  const bool is_c = (gate == 0);

  float4 wf[4][8];
#pragma unroll
  for (int j = 0; j < 4; ++j) {
    const int col = (j << 8) + g * 8 + cg;
#pragma unroll
    for (int m = 0; m < 8; ++m) {
      const int k0 = 4 * (kc + 8 * m);
      wf[j][m].x = Wr[(k0 + 0) * 1024 + col];
      wf[j][m].y = Wr[(k0 + 1) * 1024 + col];
      wf[j][m].z = Wr[(k0 + 2) * 1024 + col];
      wf[j][m].w = Wr[(k0 + 3) * 1024 + col];
    }
  }
#pragma unroll
  for (int e = 0; e < 8; ++e) hbufs[b * 260 + 8 * sc + e] = 0.0f;  // buf0 zeros

  float creg = 0.0f;
  if (cinit && is_c) creg = cinit[((b << 10) + 1023) * 256 + u];
  __syncthreads();

  for (int s = 0; s < 1024; ++s) {
    const int t = rev ? (1023 - s) : s;

    // Band gate: once per 64 steps, wait until this band's xW tiles (4 gate
    // strips x 16 batch-tiles each) are drained to L3 by the workers.
    if ((s & 63) == 0) {
      if (tid < 4) {
        const unsigned* cp = xcnt + (((t >> 6) * 8 + 2 * tid + (g >> 4)) << 4);
        unsigned v; int spin = 0;
        for (;;) {
          asm volatile("global_load_dword %0, %1, off sc0 sc1\n\ts_waitcnt vmcnt(0)"
                       : "=v"(v) : "v"(cp) : "memory");
          if (__all((int)(v >= 16u))) break;
          __builtin_amdgcn_s_sleep(1);
          if (++spin > (1 << 16)) break;  // failsafe: terminate > hang
        }
      }
      __syncthreads();
    }

    // xW prefetch (uncached; guaranteed ready by the band gate).
    float xw0, xw1, xw2, xw3;
    const float* xp = xW + (size_t)((b << 10) + t) * 1024 + u;
    if (is_c) {
      asm volatile("global_load_dword %0, %4, off sc0 sc1\n\t"
                   "global_load_dword %1, %4, off offset:1024 sc0 sc1\n\t"
                   "global_load_dword %2, %4, off offset:2048 sc0 sc1\n\t"
                   "global_load_dword %3, %4, off offset:3072 sc0 sc1"
                   : "=&v"(xw0), "=&v"(xw1), "=&v"(xw2), "=&v"(xw3)
                   : "v"(xp) : "memory");
    }

    float* hcur = hbufs + (s & 1) * (16 * 260);
    if (s > 0) {
      // Poll h[t-1]: the successful load IS the data.
      const float* rp = rg + (size_t)(s - 1) * 4096 + 8 * tid;
      float4 h0, h1;
      int spin = 0;
      for (;;) {
        asm volatile("global_load_dwordx4 %0, %2, off sc0 sc1\n\t"
                     "global_load_dwordx4 %1, %2, off offset:16 sc0 sc1\n\t"
                     "s_waitcnt vmcnt(0)"
                     : "=&v"(h0), "=&v"(h1) : "v"(rp) : "memory");
        const int bad = (__float_as_uint(h0.x) == SENTU) | (__float_as_uint(h0.y) == SENTU) |
                        (__float_as_uint(h0.z) == SENTU) | (__float_as_uint(h0.w) == SENTU) |
                        (__float_as_uint(h1.x) == SENTU) | (__float_as_uint(h1.y) == SENTU) |
                        (__float_as_uint(h1.z) == SENTU) | (__float_as_uint(h1.w) == SENTU);
        if (!__any(bad)) break;
        if (++spin > (1 << 15)) break;  // failsafe
      }
      const int tu = tid >> 1, tb0 = (tid & 1) * 8;
      hcur[(tb0 + 0) * 260 + tu] = h0.x;
      hcur[(tb0 + 1) * 260 + tu] = h0.y;
      hcur[(tb0 + 2) * 260 + tu] = h0.z;
      hcur[(tb0 + 3) * 260 + tu] = h0.w;
      hcur[(tb0 + 4) * 260 + tu] = h1.x;
      hcur[(tb0 + 5) * 260 + tu] = h1.y;
      hcur[(tb0 + 6) * 260 + tu] = h1.z;
      hcur[(tb0 + 7) * 260 + tu] = h1.w;
    }
    __syncthreads();   // the ONLY per-step barrier (transpose -> MAC)

    float pj[2][4] = {};
#pragma unroll
    for (int i = 0; i < 2; ++i) {
      const float* hrow = &hcur[(2 * bg + i) * 260];
#pragma unroll
      for (int m = 0; m < 8; ++m) {
        const float4 hv = *(const float4*)&hrow[4 * (kc + 8 * m)];
#pragma unroll
        for (int j = 0; j < 4; ++j) {
          pj[i][j] += hv.x * wf[j][m].x;
          pj[i][j] += hv.y * wf[j][m].y;
          pj[i][j] += hv.z * wf[j][m].z;
          pj[i][j] += hv.w * wf[j][m].w;
        }
      }
    }
#pragma unroll
    for (int i = 0; i < 2; ++i)
#pragma unroll
      for (int j = 0; j < 4; ++j)
        pbuf[(2 * bg + i) * 260 + (4 * cg + j) * 8 + kc] = pj[i][j];
    // pbuf producer wave == consumer wave (cg == uu): no barrier needed.

    if (is_c) {
      asm volatile("s_waitcnt vmcnt(0)" ::: "memory");  // xW prefetch landed
      float z[4];
      const float xws[4] = {xw0, xw1, xw2, xw3};
#pragma unroll
      for (int j = 0; j < 4; ++j) {
        const float4 q0 = *(const float4*)&pbuf[b * 260 + (4 * uu + j) * 8];
        const float4 q1 = *(const float4*)&pbuf[b * 260 + (4 * uu + j) * 8 + 4];
        z[j] = ((q0.x + q0.y) + (q0.z + q0.w)) +
               ((q1.x + q1.y) + (q1.z + q1.w)) + xws[j];
      }
      const float c2 = sigf(z[1]) * creg + sigf(z[0]) * tanhf(z[2]);
      const float h2 = sigf(z[3]) * tanhf(c2);
      creg = c2;
      float* rp = rg + (size_t)s * 4096 + u * 16 + b;   // data = readiness
      asm volatile("global_store_dword %0, %1, off sc0 sc1"
                   :: "v"(rp), "v"(h2) : "memory");
      if (hout) hout[((b << 10) + t) * 256 + u] = h2;   // cached; next dispatch
    }
    // no end-of-step barrier: hbuf is double-buffered, pbuf wave-private
  }
}

// ---------------- Fused decision role (512 threads, hidden under decoder) ---
__device__ void decide_role(const float* __restrict__ ringd, const float* __restrict__ b12f,
                            const float* __restrict__ b3, const float* __restrict__ W4,
                            const float* __restrict__ vt1, const float* __restrict__ vt2,
                            const float* __restrict__ cemb, float* __restrict__ out,
                            unsigned* __restrict__ doneCtr, int b,
                            float* __restrict__ smem)
{
  float* v1s  = smem;                 // 256
  float* add3 = smem + 256;           // 256
  float* hrow = smem + 512;           // 256
  float* redv = smem + 768;           // 512
  int*   redi = (int*)(smem + 1280);  // 512
  float* sc   = smem + 1792;          // [0]=out2, [1]=r(bits)
  const int tid = threadIdx.x;

  if (tid < 256) v1s[tid] = vt1[tid];
  if (tid == 0) {   // wait until all 512 b12f tiles are published
    int spin = 0;
    while (__hip_atomic_load(doneCtr, __ATOMIC_RELAXED, __HIP_MEMORY_SCOPE_AGENT) < 512u) {
      __builtin_amdgcn_s_sleep(32);
      if (++spin > (1 << 17)) break;  // failsafe
    }
  }
  __syncthreads();

  int bond = 0, last = 0;
  for (int iter = 0; iter < 1024; ++iter) {
    const int t = bond;
    if (tid < 256) {
      const float* hp = ringd + (size_t)t * 4096 + tid * 16 + b;
      float hv; int spin = 0;
      for (;;) {   // poll decoder h_t (sentinel = not yet produced)
        asm volatile("global_load_dword %0, %1, off sc0 sc1\n\ts_waitcnt vmcnt(0)"
                     : "=v"(hv) : "v"(hp) : "memory");
        if (__float_as_uint(hv) != SENTU) break;
        __builtin_amdgcn_s_sleep(2);
        if (++spin > (1 << 15)) break;  // failsafe
      }
      hrow[tid] = hv;
      redv[tid] = cemb[(t - last) * 256 + tid] * vt2[tid];
    }
    __syncthreads();
    for (int off = 128; off; off >>= 1) {
      if (tid < off) redv[tid] += redv[tid + off];
      __syncthreads();
    }
    if (tid == 0) sc[0] = redv[0];
    __syncthreads();
    if (tid < 256) {
      float a = 0.f;
#pragma unroll 4
      for (int k = 0; k < 256; ++k) a += hrow[k] * W4[k * 256 + tid];
      add3[tid] = a + b3[((b << 10) + t) * 256 + tid];
    }
    __syncthreads();
    const float out2 = sc[0];
    float best = -INFINITY; int bestj = 0x7fffffff;
    for (int j = t + tid; j < 1024; j += 512) {
      const float* row = b12f + (size_t)((b << 10) + j) * 256;
      float sacc = 0.f;
      for (int n = 0; n < 256; n += 16) {
        float4 r0, r1, r2, r3;   // uncached: b12f written sc0 sc1 in-dispatch
        asm volatile("global_load_dwordx4 %0, %4, off sc0 sc1\n\t"
                     "global_load_dwordx4 %1, %4, off offset:16 sc0 sc1\n\t"
                     "global_load_dwordx4 %2, %4, off offset:32 sc0 sc1\n\t"
                     "global_load_dwordx4 %3, %4, off offset:48 sc0 sc1\n\t"
                     "s_waitcnt vmcnt(0)"
                     : "=&v"(r0), "=&v"(r1), "=&v"(r2), "=&v"(r3)
                     : "v"(row + n) : "memory");
        sacc += tanhf(r0.x + add3[n + 0])  * v1s[n + 0];
        sacc += tanhf(r0.y + add3[n + 1])  * v1s[n + 1];
        sacc += tanhf(r0.z + add3[n + 2])  * v1s[n + 2];
        sacc += tanhf(r0.w + add3[n + 3])  * v1s[n + 3];
        sacc += tanhf(r1.x + add3[n + 4])  * v1s[n + 4];
        sacc += tanhf(r1.y + add3[n + 5])  * v1s[n + 5];
        sacc += tanhf(r1.z + add3[n + 6])  * v1s[n + 6];
        sacc += tanhf(r1.w + add3[n + 7])  * v1s[n + 7];
        sacc += tanhf(r2.x + add3[n + 8])  * v1s[n + 8];
        sacc += tanhf(r2.y + add3[n + 9])  * v1s[n + 9];
        sacc += tanhf(r2.z + add3[n + 10]) * v1s[n + 10];
        sacc += tanhf(r2.w + add3[n + 11]) * v1s[n + 11];
        sacc += tanhf(r3.x + add3[n + 12]) * v1s[n + 12];
        sacc += tanhf(r3.y + add3[n + 13]) * v1s[n + 13];
        sacc += tanhf(r3.z + add3[n + 14]) * v1s[n + 14];
        sacc += tanhf(r3.w + add3[n + 15]) * v1s[n + 15];
      }
      const float logit = sacc + out2;
      if (logit > best || (logit == best && j < bestj)) { best = logit; bestj = j; }
    }
    redv[tid] = best; redi[tid] = bestj;
    __syncthreads();
    for (int off = 256; off; off >>= 1) {
      if (tid < off) {
        const float v2 = redv[tid + off]; const int j2 = redi[tid + off];
        if (v2 > redv[tid] || (v2 == redv[tid] && j2 < redi[tid])) {
          redv[tid] = v2; redi[tid] = j2;
        }
      }
      __syncthreads();
    }
    if (tid == 0) { sc[1] = __int_as_float(redi[0]); out[redi[0] * 16 + b] = 1.0f; }
    __syncthreads();
    const int r = __float_as_int(sc[1]);
    if (r == t) break;   // bond stuck -> no further decisions
    last = t; bond = r;
    __syncthreads();
  }
}

// ---------------- Phase 1: 64 chain blocks + 192 persistent workers ---------
__global__ __launch_bounds__(512, 1)
void phase1_k(const float* __restrict__ x,
              const float* __restrict__ Wih_f, const float* __restrict__ b_f,
              const float* __restrict__ Whh_f,
              const float* __restrict__ Wih_b, const float* __restrict__ b_b,
              const float* __restrict__ Whh_b,
              const float* __restrict__ W2, const float* __restrict__ W3,
              float* __restrict__ xWf, float* __restrict__ xWb,
              float* __restrict__ b12x, float* __restrict__ b3,
              float* __restrict__ hn, float* __restrict__ hb,
              float* __restrict__ ring, unsigned* __restrict__ tcnt)
{
  __shared__ float smem[3 * 16 * 260];
  const int blk = blockIdx.x;
  if (blk < 64) {
    const int dir = blk >> 5, g = blk & 31;
    lstm_role(dir ? xWb : xWf, dir ? Whh_b : Whh_f, dir ? hb : hn, nullptr,
              ring + (size_t)dir * 1024 * 4096, tcnt + dir * 2048, g, dir, smem);
  } else {
    const int wid = blk - 64;
    for (int tile = wid; tile < 5120; tile += 192) {
      if (tile < 4096) {
        // t-banded xW tiles: fwd ascending, bwd descending
        const int band = tile >> 8, j = tile & 255;
        const int isb = j >> 7, jj = j & 127;
        const int bb = jj >> 3, np = jj & 7;
        const int t64 = isb ? (15 - band) : band;
        const int m0 = (bb << 10) + t64 * 64, n0 = np * 128;
        if (!isb) gemm_tile<0>(x, nullptr, Wih_f, b_f, xWf, 1024, 256, m0, n0, 0, 1, smem);
        else      gemm_tile<0>(x, nullptr, Wih_b, b_b, xWb, 1024, 256, m0, n0, 0, 1, smem);
        asm volatile("s_waitcnt vmcnt(0)" ::: "memory");
        __syncthreads();
        if (threadIdx.x == 0) {
          unsigned* cp = tcnt + isb * 2048 + ((t64 * 8 + np) << 4);
          __hip_atomic_fetch_add(cp, 1u, __ATOMIC_RELAXED, __HIP_MEMORY_SCOPE_AGENT);
        }
      } else {
        int k = tile - 4096;          // 0..1023: b12x / b3 interleaved (cached)
        const int which = k & 1; k >>= 1;
        const int m0 = (k >> 1) * 64, n0 = (k & 1) * 128;
        if (which) gemm_tile<0>(x, nullptr, W3, nullptr, b3, 256, 256, m0, n0, 0, 0, smem);
        else       gemm_tile<0>(x, nullptr, W2, nullptr, b12x, 256, 256, m0, n0, 0, 0, smem);
      }
    }
  }
}

// ---------------- Phase 2: 32 decoder + 16 decide + 208 workers -------------
__global__ __launch_bounds__(512, 1)
void phase2_k(const float* __restrict__ x,
              const float* __restrict__ hn, const float* __restrict__ hb,
              const float* __restrict__ dWih, const float* __restrict__ db,
              const float* __restrict__ dWhh, const float* __restrict__ W1,
              float* __restrict__ decIn, float* __restrict__ b12f,
              const float* __restrict__ b3, const float* __restrict__ W4,
              const float* __restrict__ vt1, const float* __restrict__ vt2,
              const float* __restrict__ cemb, float* __restrict__ out,
              float* __restrict__ ring2, unsigned* __restrict__ tcnt,
              unsigned* __restrict__ doneCtr)
{
  __shared__ float smem[3 * 16 * 260];
  const int blk = blockIdx.x;
  if (blk < 32) {
    lstm_role(decIn, dWhh, nullptr, hn, ring2, tcnt + 2 * 2048, blk, 0, smem);
  } else if (blk < 48) {
    decide_role(ring2, b12f, b3, W4, vt1, vt2, cemb, out, doneCtr, blk - 32, smem);
  } else {
    const int wid = blk - 48;
    for (int tile = wid; tile < 2560; tile += 208) {
      if (tile < 2048) {
        const int band = tile >> 7, j = tile & 127;
        const int bb = j >> 3, np = j & 7;
        const int m0 = (bb << 10) + band * 64, n0 = np * 128;
        gemm_tile<1>(x, hn, dWih, db, decIn, 1024, 512, m0, n0, 0, 1, smem);
        asm volatile("s_waitcnt vmcnt(0)" ::: "memory");
        __syncthreads();
        if (threadIdx.x == 0) {
          unsigned* cp = tcnt + 2 * 2048 + ((band * 8 + np) << 4);
          __hip_atomic_fetch_add(cp, 1u, __ATOMIC_RELAXED, __HIP_MEMORY_SCOPE_AGENT);
        }
      } else {
        const int k = tile - 2048;    // b12f = b12x + [hn,hb]@W1 (in place)
        const int m0 = (k >> 1) * 64, n0 = (k & 1) * 128;
        gemm_tile<2>(hn, hb, W1, nullptr, b12f, 256, 512, m0, n0, 1, 1, smem);
        asm volatile("s_waitcnt vmcnt(0)" ::: "memory");
        __syncthreads();
        if (threadIdx.x == 0)
          __hip_atomic_fetch_add(doneCtr, 1u, __ATOMIC_RELEASE, __HIP_MEMORY_SCOPE_AGENT);
      }
    }
  }
}

// ---------------------------------------------------------------------------
extern "C" void kernel_launch(void* const* d_in, const int* in_sizes, int n_in,
                              void* d_out, int out_size, void* d_ws, size_t ws_size,
                              hipStream_t stream)
{
  const float* x     = (const float*)d_in[0];
  const float* Wih_f = (const float*)d_in[1];
  const float* Whh_f = (const float*)d_in[2];
  const float* b_f   = (const float*)d_in[3];
  const float* Wih_b = (const float*)d_in[4];
  const float* Whh_b = (const float*)d_in[5];
  const float* b_b   = (const float*)d_in[6];
  const float* dWih  = (const float*)d_in[7];
  const float* dWhh  = (const float*)d_in[8];
  const float* db    = (const float*)d_in[9];
  const float* W1    = (const float*)d_in[10];
  const float* W2    = (const float*)d_in[11];
  const float* W3    = (const float*)d_in[12];
  const float* W4    = (const float*)d_in[13];
  const float* vt1   = (const float*)d_in[14];
  const float* vt2   = (const float*)d_in[15];
  const float* cemb  = (const float*)d_in[16];
  float* out = (float*)d_out;

  char* ws = (char*)d_ws;
  float*    xWf  = (float*)(ws);                        // 64 MB (aliased decIn)
  float*    xWb  = (float*)(ws + (size_t)(64u << 20));  // 64 MB
  float*    hn   = (float*)(ws + (size_t)(128u << 20)); // 16 MB
  float*    hb   = (float*)(ws + (size_t)(144u << 20)); // 16 MB
  float*    b12  = (float*)(ws + (size_t)(160u << 20)); // 16 MB (b12x -> b12f)
  float*    b3   = (float*)(ws + (size_t)(176u << 20)); // 16 MB
  float*    ring = (float*)(ws + (size_t)(192u << 20)); // 48 MB: encF, encB, dec
  unsigned* ctr  = (unsigned*)(ws + (size_t)(240u << 20));        // doneCtr
  unsigned* tcnt = (unsigned*)(ws + (size_t)(240u << 20) + 4096); // tile counters
  float* decIn = xWf;
  float* ring2 = ring + (size_t)2 * 1024 * 4096;

  // Only the rings need sentinel poison (xW buffers are counter-gated now).
  (void)hipMemsetAsync(ring, 0xAA, (size_t)3 * 1024 * 4096 * sizeof(float), stream);
  (void)hipMemsetAsync(ctr, 0, 32768, stream);   // doneCtr + 3x2048 tile counters
  (void)hipMemsetAsync(out, 0, (size_t)out_size * sizeof(float), stream);

  phase1_k<<<256, 512, 0, stream>>>(x, Wih_f, b_f, Whh_f, Wih_b, b_b, Whh_b,
                                    W2, W3, xWf, xWb, b12, b3, hn, hb, ring, tcnt);
  phase2_k<<<256, 512, 0, stream>>>(x, hn, hb, dWih, db, dWhh, W1,
                                    decIn, b12, b3, W4, vt1, vt2, cemb, out,
                                    ring2, tcnt, ctr);
}

// Round 10
// 5400.933 us; speedup vs baseline: 1.3924x; 1.3924x over previous
//
#include <hip/hip_runtime.h>
#include <math.h>

// ---------------------------------------------------------------------------
// PointerNetwork: biLSTM encoder + sequential pointer decoder (all fp32).
// R7 structure (proven): two 256-block mega-dispatches, cross-block exchange
// at the L3 coherence point (sc0 sc1), data-as-flag sentinel rings, TWO
// pacing barriers per LSTM step (R9 showed removing them regresses).
//  phase1: blk 0-63 encoder chains | 192 workers: xWf/xWb (uncached +
//          per-band tile counters), b12x=x@W2, b3=x@W3 (cached).
//  phase2: blk 0-31 decoder | blk 32-47 fused decide | 208 workers: decIn
//          (uncached + counters) then b12f = b12x + [hn,hb]@W1 (+doneCtr).
// LSTM step: k-partials reduced via wave shuffles (no pbuf LDS round-trip);
// cell runs in the compute role (lane kc<2 owns batch 2bg+kc); fast
// exp2-based sigmoid/tanh on the serial path (decide keeps libm tanh).
// NOTE: float4 ok as asm OUTPUT ("=&v"), NOT as input.
// ---------------------------------------------------------------------------

#define SENTU 0xAAAAAAAAu

__device__ __forceinline__ float sigf(float x) { return 1.0f / (1.0f + expf(-x)); }
// Fast path (LSTM cell only): ~2-3 ulp, saturates correctly for large |x|.
__device__ __forceinline__ float fsig(float x) {
  return __builtin_amdgcn_rcpf(1.0f + __expf(-x));
}
__device__ __forceinline__ float ftanh(float x) {
  return 2.0f * __builtin_amdgcn_rcpf(1.0f + __expf(-2.0f * x)) - 1.0f;
}

// ---------------- 64x128 GEMM tile, 512 threads -----------------------------
template<int SRC>
__device__ void gemm_tile(const float* __restrict__ A, const float* __restrict__ A2,
                          const float* __restrict__ B, const float* __restrict__ bias,
                          float* __restrict__ C, int N, int K,
                          int m0, int n0_base, int accum, int uncached,
                          float* __restrict__ smem)
{
  float* As = smem;                 // [16][68]
  float* Bs = smem + 16 * 68;       // [2][16][64]
  const int tid  = threadIdx.x;
  const int half = tid >> 8;
  const int htid = tid & 255;
  const int n0 = n0_base + half * 64;
  float* Bsh = Bs + half * (16 * 64);
  const int am = htid >> 2, akq = htid & 3;
  const int bkk = htid >> 4, bnq = htid & 15;
  const int tx = htid & 15, ty = htid >> 4;
  float acc[4][4] = {};
  for (int k0 = 0; k0 < K; k0 += 16) {
    const int ak = k0 + 4 * akq;
    if (half == 0) {
      const int ar = m0 + am;
      float4 av;
      if (SRC == 0) {
        av = *(const float4*)&A[(size_t)ar * K + ak];
      } else if (SRC == 1) {
        const int bb = ar >> 10, t = ar & 1023;
        if (t == 0) { av = make_float4(0.f, 0.f, 0.f, 0.f); }
        else {
          const int src = ((bb << 10) + (t - 1)) * 256;
          av = (ak < 256) ? *(const float4*)&A[src + ak]
                          : *(const float4*)&A2[src + (ak - 256)];
        }
      } else {
        const int src = ar * 256;
        av = (ak < 256) ? *(const float4*)&A[src + ak]
                        : *(const float4*)&A2[src + (ak - 256)];
      }
      As[(4 * akq + 0) * 68 + am] = av.x;
      As[(4 * akq + 1) * 68 + am] = av.y;
      As[(4 * akq + 2) * 68 + am] = av.z;
      As[(4 * akq + 3) * 68 + am] = av.w;
    }
    const float4 bv = *(const float4*)&B[(size_t)(k0 + bkk) * N + n0 + 4 * bnq];
    *(float4*)&Bsh[bkk * 64 + 4 * bnq] = bv;
    __syncthreads();
#pragma unroll
    for (int kk = 0; kk < 16; ++kk) {
      const float4 a = *(const float4*)&As[kk * 68 + 4 * ty];
      const float4 b = *(const float4*)&Bsh[kk * 64 + 4 * tx];
      acc[0][0] += a.x * b.x; acc[0][1] += a.x * b.y; acc[0][2] += a.x * b.z; acc[0][3] += a.x * b.w;
      acc[1][0] += a.y * b.x; acc[1][1] += a.y * b.y; acc[1][2] += a.y * b.z; acc[1][3] += a.y * b.w;
      acc[2][0] += a.z * b.x; acc[2][1] += a.z * b.y; acc[2][2] += a.z * b.z; acc[2][3] += a.z * b.w;
      acc[3][0] += a.w * b.x; acc[3][1] += a.w * b.y; acc[3][2] += a.w * b.z; acc[3][3] += a.w * b.w;
    }
    __syncthreads();
  }
  const float4 bsv = bias ? *(const float4*)&bias[n0 + 4 * tx] : make_float4(0.f, 0.f, 0.f, 0.f);
#pragma unroll
  for (int i = 0; i < 4; ++i) {
    float* crow = &C[(size_t)(m0 + 4 * ty + i) * N + n0 + 4 * tx];
    float4 old = accum ? *(const float4*)crow : make_float4(0.f, 0.f, 0.f, 0.f);
    float4 r;
    r.x = acc[i][0] + old.x + bsv.x;
    r.y = acc[i][1] + old.y + bsv.y;
    r.z = acc[i][2] + old.z + bsv.z;
    r.w = acc[i][3] + old.w + bsv.w;
    if (uncached) {
      asm volatile("global_store_dword %0, %1, off sc0 sc1"
                   :: "v"(crow), "v"(r.x) : "memory");
      asm volatile("global_store_dword %0, %1, off offset:4 sc0 sc1"
                   :: "v"(crow), "v"(r.y) : "memory");
      asm volatile("global_store_dword %0, %1, off offset:8 sc0 sc1"
                   :: "v"(crow), "v"(r.z) : "memory");
      asm volatile("global_store_dword %0, %1, off offset:12 sc0 sc1"
                   :: "v"(crow), "v"(r.w) : "memory");
    } else {
      *(float4*)crow = r;
    }
  }
}

// ---------------- Sequential LSTM role --------------------------------------
// 512 threads, compute role tid = cg*64 + bg*8 + kc. Wave cg owns unit
// u = g*8+cg (4 gate-cols). k-partials reduced by an 8-lane shfl butterfly
// (round 1 swaps i so lane kc accumulates batch-parity kc&1); lanes kc<2
// run the cell for batch 2bg+kc and publish one dword of the wave's 64B
// ring line. Two pacing barriers per step (R7 semantics — R9 proved the
// end barrier is part of the sync fabric).
__device__ void lstm_role(const float* __restrict__ xW, const float* __restrict__ Wr,
                          float* __restrict__ hout, const float* __restrict__ cinit,
                          float* __restrict__ rg, const unsigned* __restrict__ xcnt,
                          int g, int rev, float* __restrict__ smem)
{
  float* hbuf = smem;                   // h[b][k], stride 260

  const int tid = threadIdx.x;
  const int kc = tid & 7;
  const int bg = (tid >> 3) & 7;
  const int cg = tid >> 6;              // wave id
  const int b16 = tid & 15;             // zero-init helper role
  const int sc  = tid >> 4;
  const int u    = g * 8 + cg;          // this wave's hidden unit
  const int bloc = 2 * bg + kc;         // batch index (valid when kc<2)
  const bool do_cell = (kc < 2);

  float4 wf[4][8];
#pragma unroll
  for (int j = 0; j < 4; ++j) {
    const int col = (j << 8) + g * 8 + cg;
#pragma unroll
    for (int m = 0; m < 8; ++m) {
      const int k0 = 4 * (kc + 8 * m);
      wf[j][m].x = Wr[(k0 + 0) * 1024 + col];
      wf[j][m].y = Wr[(k0 + 1) * 1024 + col];
      wf[j][m].z = Wr[(k0 + 2) * 1024 + col];
      wf[j][m].w = Wr[(k0 + 3) * 1024 + col];
    }
  }
#pragma unroll
  for (int e = 0; e < 8; ++e) hbuf[b16 * 260 + 8 * sc + e] = 0.0f;

  float creg = 0.0f;
  if (cinit && do_cell) creg = cinit[((bloc << 10) + 1023) * 256 + u];
  __syncthreads();

  for (int s = 0; s < 1024; ++s) {
    const int t = rev ? (1023 - s) : s;

    // Band gate: once per 64 steps, wait until this band's xW tiles are
    // drained to L3 by the workers (per-strip counters reach 16).
    if ((s & 63) == 0) {
      if (tid < 4) {
        const unsigned* cp = xcnt + (((t >> 6) * 8 + 2 * tid + (g >> 4)) << 4);
        unsigned v; int spin = 0;
        for (;;) {
          asm volatile("global_load_dword %0, %1, off sc0 sc1\n\ts_waitcnt vmcnt(0)"
                       : "=v"(v) : "v"(cp) : "memory");
          if (__all((int)(v >= 16u))) break;
          __builtin_amdgcn_s_sleep(1);
          if (++spin > (1 << 16)) break;  // failsafe: terminate > hang
        }
      }
      __syncthreads();
    }

    // xW prefetch (uncached; ready by the band gate). One load per gate.
    float xw0, xw1, xw2, xw3;
    const float* xp = xW + (size_t)((bloc << 10) + t) * 1024 + u;
    if (do_cell) {
      asm volatile("global_load_dword %0, %4, off sc0 sc1\n\t"
                   "global_load_dword %1, %4, off offset:1024 sc0 sc1\n\t"
                   "global_load_dword %2, %4, off offset:2048 sc0 sc1\n\t"
                   "global_load_dword %3, %4, off offset:3072 sc0 sc1"
                   : "=&v"(xw0), "=&v"(xw1), "=&v"(xw2), "=&v"(xw3)
                   : "v"(xp) : "memory");
    }

    if (s > 0) {
      // Poll h[t-1]: the successful load IS the data.
      const float* rp = rg + (size_t)(s - 1) * 4096 + 8 * tid;
      float4 h0, h1;
      int spin = 0;
      for (;;) {
        asm volatile("global_load_dwordx4 %0, %2, off sc0 sc1\n\t"
                     "global_load_dwordx4 %1, %2, off offset:16 sc0 sc1\n\t"
                     "s_waitcnt vmcnt(0)"
                     : "=&v"(h0), "=&v"(h1) : "v"(rp) : "memory");
        const int bad = (__float_as_uint(h0.x) == SENTU) | (__float_as_uint(h0.y) == SENTU) |
                        (__float_as_uint(h0.z) == SENTU) | (__float_as_uint(h0.w) == SENTU) |
                        (__float_as_uint(h1.x) == SENTU) | (__float_as_uint(h1.y) == SENTU) |
                        (__float_as_uint(h1.z) == SENTU) | (__float_as_uint(h1.w) == SENTU);
        if (!__any(bad)) break;
        if (++spin > (1 << 15)) break;  // failsafe
      }
      const int tu = tid >> 1, tb0 = (tid & 1) * 8;
      hbuf[(tb0 + 0) * 260 + tu] = h0.x;
      hbuf[(tb0 + 1) * 260 + tu] = h0.y;
      hbuf[(tb0 + 2) * 260 + tu] = h0.z;
      hbuf[(tb0 + 3) * 260 + tu] = h0.w;
      hbuf[(tb0 + 4) * 260 + tu] = h1.x;
      hbuf[(tb0 + 5) * 260 + tu] = h1.y;
      hbuf[(tb0 + 6) * 260 + tu] = h1.z;
      hbuf[(tb0 + 7) * 260 + tu] = h1.w;
    }
    __syncthreads();   // barrier 1: transpose -> MAC

    float pj[2][4] = {};
#pragma unroll
    for (int i = 0; i < 2; ++i) {
      const float* hrow = &hbuf[(2 * bg + i) * 260];
#pragma unroll
      for (int m = 0; m < 8; ++m) {
        const float4 hv = *(const float4*)&hrow[4 * (kc + 8 * m)];
#pragma unroll
        for (int j = 0; j < 4; ++j) {
          pj[i][j] += hv.x * wf[j][m].x;
          pj[i][j] += hv.y * wf[j][m].y;
          pj[i][j] += hv.z * wf[j][m].z;
          pj[i][j] += hv.w * wf[j][m].w;
        }
      }
    }

    // 8-lane butterfly: round 1 exchanges the "other parity" partial so lane
    // kc ends with the full sum for batch parity kc&1; rounds 2-3 sum across
    // the remaining kc lanes. Lane kc holds S[kc&1][j] afterwards.
    const int myi = kc & 1;
    float zv[4];
#pragma unroll
    for (int j = 0; j < 4; ++j) {
      const float mine  = myi ? pj[1][j] : pj[0][j];
      const float other = myi ? pj[0][j] : pj[1][j];
      float v = mine + __shfl_xor(other, 1);
      v += __shfl_xor(v, 2);
      v += __shfl_xor(v, 4);
      zv[j] = v;
    }

    if (do_cell) {
      asm volatile("s_waitcnt vmcnt(0)" ::: "memory");  // xW prefetch landed
      const float z0 = zv[0] + xw0;
      const float z1 = zv[1] + xw1;
      const float z2 = zv[2] + xw2;
      const float z3 = zv[3] + xw3;
      const float c2 = fsig(z1) * creg + fsig(z0) * ftanh(z2);
      const float h2 = fsig(z3) * ftanh(c2);
      creg = c2;
      float* rp = rg + (size_t)s * 4096 + u * 16 + bloc;   // data = readiness
      asm volatile("global_store_dword %0, %1, off sc0 sc1"
                   :: "v"(rp), "v"(h2) : "memory");
      if (hout) hout[((bloc << 10) + t) * 256 + u] = h2;   // cached; next dispatch
    }
    __syncthreads();   // barrier 2: pacing + hbuf protection (R7 semantics)
  }
}

// ---------------- Fused decision role (512 threads, hidden under decoder) ---
__device__ void decide_role(const float* __restrict__ ringd, const float* __restrict__ b12f,
                            const float* __restrict__ b3, const float* __restrict__ W4,
                            const float* __restrict__ vt1, const float* __restrict__ vt2,
                            const float* __restrict__ cemb, float* __restrict__ out,
                            unsigned* __restrict__ doneCtr, int b,
                            float* __restrict__ smem)
{
  float* v1s  = smem;                 // 256
  float* add3 = smem + 256;           // 256
  float* hrow = smem + 512;           // 256
  float* redv = smem + 768;           // 512
  int*   redi = (int*)(smem + 1280);  // 512
  float* sc   = smem + 1792;          // [0]=out2, [1]=r(bits)
  const int tid = threadIdx.x;

  if (tid < 256) v1s[tid] = vt1[tid];
  if (tid == 0) {   // wait until all 512 b12f tiles are published
    int spin = 0;
    while (__hip_atomic_load(doneCtr, __ATOMIC_RELAXED, __HIP_MEMORY_SCOPE_AGENT) < 512u) {
      __builtin_amdgcn_s_sleep(32);
      if (++spin > (1 << 17)) break;  // failsafe
    }
  }
  __syncthreads();

  int bond = 0, last = 0;
  for (int iter = 0; iter < 1024; ++iter) {
    const int t = bond;
    if (tid < 256) {
      const float* hp = ringd + (size_t)t * 4096 + tid * 16 + b;
      float hv; int spin = 0;
      for (;;) {   // poll decoder h_t (sentinel = not yet produced)
        asm volatile("global_load_dword %0, %1, off sc0 sc1\n\ts_waitcnt vmcnt(0)"
                     : "=v"(hv) : "v"(hp) : "memory");
        if (__float_as_uint(hv) != SENTU) break;
        __builtin_amdgcn_s_sleep(2);
        if (++spin > (1 << 15)) break;  // failsafe
      }
      hrow[tid] = hv;
      redv[tid] = cemb[(t - last) * 256 + tid] * vt2[tid];
    }
    __syncthreads();
    for (int off = 128; off; off >>= 1) {
      if (tid < off) redv[tid] += redv[tid + off];
      __syncthreads();
    }
    if (tid == 0) sc[0] = redv[0];
    __syncthreads();
    if (tid < 256) {
      float a = 0.f;
#pragma unroll 4
      for (int k = 0; k < 256; ++k) a += hrow[k] * W4[k * 256 + tid];
      add3[tid] = a + b3[((b << 10) + t) * 256 + tid];
    }
    __syncthreads();
    const float out2 = sc[0];
    float best = -INFINITY; int bestj = 0x7fffffff;
    for (int j = t + tid; j < 1024; j += 512) {
      const float* row = b12f + (size_t)((b << 10) + j) * 256;
      float sacc = 0.f;
      for (int n = 0; n < 256; n += 16) {
        float4 r0, r1, r2, r3;   // uncached: b12f written sc0 sc1 in-dispatch
        asm volatile("global_load_dwordx4 %0, %4, off sc0 sc1\n\t"
                     "global_load_dwordx4 %1, %4, off offset:16 sc0 sc1\n\t"
                     "global_load_dwordx4 %2, %4, off offset:32 sc0 sc1\n\t"
                     "global_load_dwordx4 %3, %4, off offset:48 sc0 sc1\n\t"
                     "s_waitcnt vmcnt(0)"
                     : "=&v"(r0), "=&v"(r1), "=&v"(r2), "=&v"(r3)
                     : "v"(row + n) : "memory");
        sacc += tanhf(r0.x + add3[n + 0])  * v1s[n + 0];
        sacc += tanhf(r0.y + add3[n + 1])  * v1s[n + 1];
        sacc += tanhf(r0.z + add3[n + 2])  * v1s[n + 2];
        sacc += tanhf(r0.w + add3[n + 3])  * v1s[n + 3];
        sacc += tanhf(r1.x + add3[n + 4])  * v1s[n + 4];
        sacc += tanhf(r1.y + add3[n + 5])  * v1s[n + 5];
        sacc += tanhf(r1.z + add3[n + 6])  * v1s[n + 6];
        sacc += tanhf(r1.w + add3[n + 7])  * v1s[n + 7];
        sacc += tanhf(r2.x + add3[n + 8])  * v1s[n + 8];
        sacc += tanhf(r2.y + add3[n + 9])  * v1s[n + 9];
        sacc += tanhf(r2.z + add3[n + 10]) * v1s[n + 10];
        sacc += tanhf(r2.w + add3[n + 11]) * v1s[n + 11];
        sacc += tanhf(r3.x + add3[n + 12]) * v1s[n + 12];
        sacc += tanhf(r3.y + add3[n + 13]) * v1s[n + 13];
        sacc += tanhf(r3.z + add3[n + 14]) * v1s[n + 14];
        sacc += tanhf(r3.w + add3[n + 15]) * v1s[n + 15];
      }
      const float logit = sacc + out2;
      if (logit > best || (logit == best && j < bestj)) { best = logit; bestj = j; }
    }
    redv[tid] = best; redi[tid] = bestj;
    __syncthreads();
    for (int off = 256; off; off >>= 1) {
      if (tid < off) {
        const float v2 = redv[tid + off]; const int j2 = redi[tid + off];
        if (v2 > redv[tid] || (v2 == redv[tid] && j2 < redi[tid])) {
          redv[tid] = v2; redi[tid] = j2;
        }
      }
      __syncthreads();
    }
    if (tid == 0) { sc[1] = __int_as_float(redi[0]); out[redi[0] * 16 + b] = 1.0f; }
    __syncthreads();
    const int r = __float_as_int(sc[1]);
    if (r == t) break;   // bond stuck -> no further decisions
    last = t; bond = r;
    __syncthreads();
  }
}

// ---------------- Phase 1: 64 chain blocks + 192 persistent workers ---------
__global__ __launch_bounds__(512, 1)
void phase1_k(const float* __restrict__ x,
              const float* __restrict__ Wih_f, const float* __restrict__ b_f,
              const float* __restrict__ Whh_f,
              const float* __restrict__ Wih_b, const float* __restrict__ b_b,
              const float* __restrict__ Whh_b,
              const float* __restrict__ W2, const float* __restrict__ W3,
              float* __restrict__ xWf, float* __restrict__ xWb,
              float* __restrict__ b12x, float* __restrict__ b3,
              float* __restrict__ hn, float* __restrict__ hb,
              float* __restrict__ ring, unsigned* __restrict__ tcnt)
{
  __shared__ float smem[16 * 260];
  const int blk = blockIdx.x;
  if (blk < 64) {
    const int dir = blk >> 5, g = blk & 31;
    lstm_role(dir ? xWb : xWf, dir ? Whh_b : Whh_f, dir ? hb : hn, nullptr,
              ring + (size_t)dir * 1024 * 4096, tcnt + dir * 2048, g, dir, smem);
  } else {
    const int wid = blk - 64;
    for (int tile = wid; tile < 5120; tile += 192) {
      if (tile < 4096) {
        // t-banded xW tiles: fwd ascending, bwd descending
        const int band = tile >> 8, j = tile & 255;
        const int isb = j >> 7, jj = j & 127;
        const int bb = jj >> 3, np = jj & 7;
        const int t64 = isb ? (15 - band) : band;
        const int m0 = (bb << 10) + t64 * 64, n0 = np * 128;
        if (!isb) gemm_tile<0>(x, nullptr, Wih_f, b_f, xWf, 1024, 256, m0, n0, 0, 1, smem);
        else      gemm_tile<0>(x, nullptr, Wih_b, b_b, xWb, 1024, 256, m0, n0, 0, 1, smem);
        asm volatile("s_waitcnt vmcnt(0)" ::: "memory");
        __syncthreads();
        if (threadIdx.x == 0) {
          unsigned* cp = tcnt + isb * 2048 + ((t64 * 8 + np) << 4);
          __hip_atomic_fetch_add(cp, 1u, __ATOMIC_RELAXED, __HIP_MEMORY_SCOPE_AGENT);
        }
      } else {
        int k = tile - 4096;          // 0..1023: b12x / b3 interleaved (cached)
        const int which = k & 1; k >>= 1;
        const int m0 = (k >> 1) * 64, n0 = (k & 1) * 128;
        if (which) gemm_tile<0>(x, nullptr, W3, nullptr, b3, 256, 256, m0, n0, 0, 0, smem);
        else       gemm_tile<0>(x, nullptr, W2, nullptr, b12x, 256, 256, m0, n0, 0, 0, smem);
      }
    }
  }
}

// ---------------- Phase 2: 32 decoder + 16 decide + 208 workers -------------
__global__ __launch_bounds__(512, 1)
void phase2_k(const float* __restrict__ x,
              const float* __restrict__ hn, const float* __restrict__ hb,
              const float* __restrict__ dWih, const float* __restrict__ db,
              const float* __restrict__ dWhh, const float* __restrict__ W1,
              float* __restrict__ decIn, float* __restrict__ b12f,
              const float* __restrict__ b3, const float* __restrict__ W4,
              const float* __restrict__ vt1, const float* __restrict__ vt2,
              const float* __restrict__ cemb, float* __restrict__ out,
              float* __restrict__ ring2, unsigned* __restrict__ tcnt,
              unsigned* __restrict__ doneCtr)
{
  __shared__ float smem[16 * 260];
  const int blk = blockIdx.x;
  if (blk < 32) {
    lstm_role(decIn, dWhh, nullptr, hn, ring2, tcnt + 2 * 2048, blk, 0, smem);
  } else if (blk < 48) {
    decide_role(ring2, b12f, b3, W4, vt1, vt2, cemb, out, doneCtr, blk - 32, smem);
  } else {
    const int wid = blk - 48;
    for (int tile = wid; tile < 2560; tile += 208) {
      if (tile < 2048) {
        const int band = tile >> 7, j = tile & 127;
        const int bb = j >> 3, np = j & 7;
        const int m0 = (bb << 10) + band * 64, n0 = np * 128;
        gemm_tile<1>(x, hn, dWih, db, decIn, 1024, 512, m0, n0, 0, 1, smem);
        asm volatile("s_waitcnt vmcnt(0)" ::: "memory");
        __syncthreads();
        if (threadIdx.x == 0) {
          unsigned* cp = tcnt + 2 * 2048 + ((band * 8 + np) << 4);
          __hip_atomic_fetch_add(cp, 1u, __ATOMIC_RELAXED, __HIP_MEMORY_SCOPE_AGENT);
        }
      } else {
        const int k = tile - 2048;    // b12f = b12x + [hn,hb]@W1 (in place)
        const int m0 = (k >> 1) * 64, n0 = (k & 1) * 128;
        gemm_tile<2>(hn, hb, W1, nullptr, b12f, 256, 512, m0, n0, 1, 1, smem);
        asm volatile("s_waitcnt vmcnt(0)" ::: "memory");
        __syncthreads();
        if (threadIdx.x == 0)
          __hip_atomic_fetch_add(doneCtr, 1u, __ATOMIC_RELEASE, __HIP_MEMORY_SCOPE_AGENT);
      }
    }
  }
}

// ---------------------------------------------------------------------------
extern "C" void kernel_launch(void* const* d_in, const int* in_sizes, int n_in,
                              void* d_out, int out_size, void* d_ws, size_t ws_size,
                              hipStream_t stream)
{
  const float* x     = (const float*)d_in[0];
  const float* Wih_f = (const float*)d_in[1];
  const float* Whh_f = (const float*)d_in[2];
  const float* b_f   = (const float*)d_in[3];
  const float* Wih_b = (const float*)d_in[4];
  const float* Whh_b = (const float*)d_in[5];
  const float* b_b   = (const float*)d_in[6];
  const float* dWih  = (const float*)d_in[7];
  const float* dWhh  = (const float*)d_in[8];
  const float* db    = (const float*)d_in[9];
  const float* W1    = (const float*)d_in[10];
  const float* W2    = (const float*)d_in[11];
  const float* W3    = (const float*)d_in[12];
  const float* W4    = (const float*)d_in[13];
  const float* vt1   = (const float*)d_in[14];
  const float* vt2   = (const float*)d_in[15];
  const float* cemb  = (const float*)d_in[16];
  float* out = (float*)d_out;

  char* ws = (char*)d_ws;
  float*    xWf  = (float*)(ws);                        // 64 MB (aliased decIn)
  float*    xWb  = (float*)(ws + (size_t)(64u << 20));  // 64 MB
  float*    hn   = (float*)(ws + (size_t)(128u << 20)); // 16 MB
  float*    hb   = (float*)(ws + (size_t)(144u << 20)); // 16 MB
  float*    b12  = (float*)(ws + (size_t)(160u << 20)); // 16 MB (b12x -> b12f)
  float*    b3   = (float*)(ws + (size_t)(176u << 20)); // 16 MB
  float*    ring = (float*)(ws + (size_t)(192u << 20)); // 48 MB: encF, encB, dec
  unsigned* ctr  = (unsigned*)(ws + (size_t)(240u << 20));        // doneCtr
  unsigned* tcnt = (unsigned*)(ws + (size_t)(240u << 20) + 4096); // tile counters
  float* decIn = xWf;
  float* ring2 = ring + (size_t)2 * 1024 * 4096;

  // Only the rings need sentinel poison (xW buffers are counter-gated).
  (void)hipMemsetAsync(ring, 0xAA, (size_t)3 * 1024 * 4096 * sizeof(float), stream);
  (void)hipMemsetAsync(ctr, 0, 32768, stream);   // doneCtr + 3x2048 tile counters
  (void)hipMemsetAsync(out, 0, (size_t)out_size * sizeof(float), stream);

  phase1_k<<<256, 512, 0, stream>>>(x, Wih_f, b_f, Whh_f, Wih_b, b_b, Whh_b,
                                    W2, W3, xWf, xWb, b12, b3, hn, hb, ring, tcnt);
  phase2_k<<<256, 512, 0, stream>>>(x, hn, hb, dWih, db, dWhh, W1,
                                    decIn, b12, b3, W4, vt1, vt2, cemb, out,
                                    ring2, tcnt, ctr);
}

// Round 11
// 4033.588 us; speedup vs baseline: 1.8644x; 1.3390x over previous
//
#include <hip/hip_runtime.h>
#include <math.h>

// ---------------------------------------------------------------------------
// PointerNetwork: biLSTM encoder + sequential pointer decoder (all fp32).
// KEY STRUCTURE (R11): the batch dim is parallel — one LSTM chain per
// (dir, batch), 4 blocks per chain (64 units each, weights in VGPRs).
// Per-step exchange = 256 floats among 4 blocks via a never-reused ring with
// 0xAA data-as-flag sentinel polling at the L3 coherence point (sc0 sc1).
// h layout [b][t][u] everywhere: no transpose, contiguous decide reads.
//  phase1 (256 blk): 0-127 encoder chains (dir=blk>>6, b=(blk>>2)&15,
//          seg=blk&3) | 128 workers: xWf/xWb (uncached + per-(dir,b,band)
//          counters), b12x=x@W2, b3=x@W3 (cached).
//  phase2 (256 blk): 0-63 decoder chains | 64-79 fused decide | 176 workers:
//          decIn (uncached + counters) then b12f = b12x + [hn,hb]@W1 (+doneCtr).
// Two pacing barriers per LSTM step (R9 proved they are part of the fabric).
// NOTE: float4 ok as asm OUTPUT ("=&v"), NOT as input.
// ---------------------------------------------------------------------------

#define SENTU 0xAAAAAAAAu

// Fast path (LSTM cell only): ~2-3 ulp, saturates correctly for large |x|.
__device__ __forceinline__ float fsig(float x) {
  return __builtin_amdgcn_rcpf(1.0f + __expf(-x));
}
__device__ __forceinline__ float ftanh(float x) {
  return 2.0f * __builtin_amdgcn_rcpf(1.0f + __expf(-2.0f * x)) - 1.0f;
}

// ---------------- 64x128 GEMM tile, 512 threads -----------------------------
template<int SRC>
__device__ void gemm_tile(const float* __restrict__ A, const float* __restrict__ A2,
                          const float* __restrict__ B, const float* __restrict__ bias,
                          float* __restrict__ C, int N, int K,
                          int m0, int n0_base, int accum, int uncached,
                          float* __restrict__ smem)
{
  float* As = smem;                 // [16][68]
  float* Bs = smem + 16 * 68;       // [2][16][64]
  const int tid  = threadIdx.x;
  const int half = tid >> 8;
  const int htid = tid & 255;
  const int n0 = n0_base + half * 64;
  float* Bsh = Bs + half * (16 * 64);
  const int am = htid >> 2, akq = htid & 3;
  const int bkk = htid >> 4, bnq = htid & 15;
  const int tx = htid & 15, ty = htid >> 4;
  float acc[4][4] = {};
  for (int k0 = 0; k0 < K; k0 += 16) {
    const int ak = k0 + 4 * akq;
    if (half == 0) {
      const int ar = m0 + am;
      float4 av;
      if (SRC == 0) {
        av = *(const float4*)&A[(size_t)ar * K + ak];
      } else if (SRC == 1) {
        const int bb = ar >> 10, t = ar & 1023;
        if (t == 0) { av = make_float4(0.f, 0.f, 0.f, 0.f); }
        else {
          const int src = ((bb << 10) + (t - 1)) * 256;
          av = (ak < 256) ? *(const float4*)&A[src + ak]
                          : *(const float4*)&A2[src + (ak - 256)];
        }
      } else {
        const int src = ar * 256;
        av = (ak < 256) ? *(const float4*)&A[src + ak]
                        : *(const float4*)&A2[src + (ak - 256)];
      }
      As[(4 * akq + 0) * 68 + am] = av.x;
      As[(4 * akq + 1) * 68 + am] = av.y;
      As[(4 * akq + 2) * 68 + am] = av.z;
      As[(4 * akq + 3) * 68 + am] = av.w;
    }
    const float4 bv = *(const float4*)&B[(size_t)(k0 + bkk) * N + n0 + 4 * bnq];
    *(float4*)&Bsh[bkk * 64 + 4 * bnq] = bv;
    __syncthreads();
#pragma unroll
    for (int kk = 0; kk < 16; ++kk) {
      const float4 a = *(const float4*)&As[kk * 68 + 4 * ty];
      const float4 b = *(const float4*)&Bsh[kk * 64 + 4 * tx];
      acc[0][0] += a.x * b.x; acc[0][1] += a.x * b.y; acc[0][2] += a.x * b.z; acc[0][3] += a.x * b.w;
      acc[1][0] += a.y * b.x; acc[1][1] += a.y * b.y; acc[1][2] += a.y * b.z; acc[1][3] += a.y * b.w;
      acc[2][0] += a.z * b.x; acc[2][1] += a.z * b.y; acc[2][2] += a.z * b.z; acc[2][3] += a.z * b.w;
      acc[3][0] += a.w * b.x; acc[3][1] += a.w * b.y; acc[3][2] += a.w * b.z; acc[3][3] += a.w * b.w;
    }
    __syncthreads();
  }
  const float4 bsv = bias ? *(const float4*)&bias[n0 + 4 * tx] : make_float4(0.f, 0.f, 0.f, 0.f);
#pragma unroll
  for (int i = 0; i < 4; ++i) {
    float* crow = &C[(size_t)(m0 + 4 * ty + i) * N + n0 + 4 * tx];
    float4 old = accum ? *(const float4*)crow : make_float4(0.f, 0.f, 0.f, 0.f);
    float4 r;
    r.x = acc[i][0] + old.x + bsv.x;
    r.y = acc[i][1] + old.y + bsv.y;
    r.z = acc[i][2] + old.z + bsv.z;
    r.w = acc[i][3] + old.w + bsv.w;
    if (uncached) {
      asm volatile("global_store_dword %0, %1, off sc0 sc1"
                   :: "v"(crow), "v"(r.x) : "memory");
      asm volatile("global_store_dword %0, %1, off offset:4 sc0 sc1"
                   :: "v"(crow), "v"(r.y) : "memory");
      asm volatile("global_store_dword %0, %1, off offset:8 sc0 sc1"
                   :: "v"(crow), "v"(r.z) : "memory");
      asm volatile("global_store_dword %0, %1, off offset:12 sc0 sc1"
                   :: "v"(crow), "v"(r.w) : "memory");
    } else {
      *(float4*)crow = r;
    }
  }
}

// ---------------- Sequential LSTM role: one chain = (dir, batch), 4 blocks --
// Block owns 64 units (g0..g0+63) = 256 gate-cols, K=256. Thread layout:
// lc = 32*wave + (lane>>1) (local col), khalf = lane&1 (k half). Weights
// wf[32] float4 = 128 VGPRs. Reduce: shfl_xor(1); gate gather: 4 shfl within
// the 8-lane unit group; lanes lane%8==0 run the cell for unit g0+8w+(lane>>3).
// Ring slot = 256 floats [u]; publish 32 B/wave; poll 64 dwords/wave.
__device__ void lstm_role(const float* __restrict__ xW, const float* __restrict__ Wr,
                          float* __restrict__ hout, const float* __restrict__ cinit,
                          float* __restrict__ rc,            // chain ring [1024][256]
                          const unsigned* __restrict__ xcnt, // per-chain band ctrs (x16)
                          int b, int g0, int rev, float* __restrict__ smem)
{
  float* hbuf = smem;   // h_prev[256]

  const int tid = threadIdx.x;
  const int l = tid & 63, w = tid >> 6;
  const int lc = 32 * w + (l >> 1);
  const int khalf = l & 1;
  const int uloc = lc >> 2, gate = lc & 3;
  const int col = (gate << 8) + g0 + uloc;
  const int lbase = l & 56;
  const bool do_cell = ((l & 7) == 0);
  const int u = g0 + 8 * w + (l >> 3);   // valid for cell lanes

  float4 wf[32];
#pragma unroll
  for (int m = 0; m < 32; ++m) {
    const int k0 = khalf * 128 + 4 * m;
    wf[m].x = Wr[(k0 + 0) * 1024 + col];
    wf[m].y = Wr[(k0 + 1) * 1024 + col];
    wf[m].z = Wr[(k0 + 2) * 1024 + col];
    wf[m].w = Wr[(k0 + 3) * 1024 + col];
  }
  if (tid < 256) hbuf[tid] = 0.0f;

  float creg = 0.0f;
  if (cinit && do_cell) creg = cinit[((b << 10) + 1023) * 256 + u];
  __syncthreads();

  for (int s = 0; s < 1024; ++s) {
    const int t = rev ? (1023 - s) : s;

    // Band gate: once per 64 steps wait for this chain's xW band (8 n-strips).
    if ((s & 63) == 0) {
      if (tid == 0) {
        const unsigned* cp = xcnt + ((t >> 6) << 4);
        unsigned v; int spin = 0;
        for (;;) {
          asm volatile("global_load_dword %0, %1, off sc0 sc1\n\ts_waitcnt vmcnt(0)"
                       : "=v"(v) : "v"(cp) : "memory");
          if (v >= 8u) break;
          __builtin_amdgcn_s_sleep(1);
          if (++spin > (1 << 16)) break;  // failsafe: terminate > hang
        }
      }
      __syncthreads();
    }

    // xW prefetch (uncached; ready by the band gate). 4 gates per cell lane.
    float xw0, xw1, xw2, xw3;
    const float* xp = xW + (size_t)((b << 10) + t) * 1024 + u;
    if (do_cell) {
      asm volatile("global_load_dword %0, %4, off sc0 sc1\n\t"
                   "global_load_dword %1, %4, off offset:1024 sc0 sc1\n\t"
                   "global_load_dword %2, %4, off offset:2048 sc0 sc1\n\t"
                   "global_load_dword %3, %4, off offset:3072 sc0 sc1"
                   : "=&v"(xw0), "=&v"(xw1), "=&v"(xw2), "=&v"(xw3)
                   : "v"(xp) : "memory");
    }

    if (s > 0) {
      // Poll h[t-1] (256 floats; each wave independently covers 64 dwords,
      // waves 4-7 duplicate 0-3 — benign). Successful load IS the data.
      const float* rp = rc + (size_t)(s - 1) * 256 + (tid & 255);
      float hv; int spin = 0;
      for (;;) {
        asm volatile("global_load_dword %0, %1, off sc0 sc1\n\ts_waitcnt vmcnt(0)"
                     : "=v"(hv) : "v"(rp) : "memory");
        if (__all((int)(__float_as_uint(hv) != SENTU))) break;
        if (++spin > (1 << 15)) break;  // failsafe
      }
      hbuf[tid & 255] = hv;
    }
    __syncthreads();   // barrier 1: h visible -> MAC

    // MAC: z_partial[col] over this thread's 128 k (broadcast LDS reads).
    float pj = 0.0f;
    const float4* h4 = (const float4*)hbuf + khalf * 32;
#pragma unroll
    for (int m = 0; m < 32; ++m) {
      const float4 hv = h4[m];
      pj += hv.x * wf[m].x + hv.y * wf[m].y + hv.z * wf[m].z + hv.w * wf[m].w;
    }
    const float v = pj + __shfl_xor(pj, 1);   // full-K z for col lc
    // gather the 4 gate z's of this 8-lane group's unit
    const float z0g = __shfl(v, lbase + 0);
    const float z1g = __shfl(v, lbase + 2);
    const float z2g = __shfl(v, lbase + 4);
    const float z3g = __shfl(v, lbase + 6);

    if (do_cell) {
      asm volatile("s_waitcnt vmcnt(0)" ::: "memory");  // xW landed
      const float z0 = z0g + xw0;   // i
      const float z1 = z1g + xw1;   // f
      const float z2 = z2g + xw2;   // g
      const float z3 = z3g + xw3;   // o
      const float c2 = fsig(z1) * creg + fsig(z0) * ftanh(z2);
      const float h2 = fsig(z3) * ftanh(c2);
      creg = c2;
      float* rp2 = rc + (size_t)s * 256 + u;   // data = readiness
      asm volatile("global_store_dword %0, %1, off sc0 sc1"
                   :: "v"(rp2), "v"(h2) : "memory");
      if (hout) hout[((b << 10) + t) * 256 + u] = h2;   // cached; next dispatch
    }
    __syncthreads();   // barrier 2: pacing + hbuf protection
  }
}

// ---------------- Fused decision role (512 threads, hidden under decoder) ---
__device__ void decide_role(const float* __restrict__ ringd, const float* __restrict__ b12f,
                            const float* __restrict__ b3, const float* __restrict__ W4,
                            const float* __restrict__ vt1, const float* __restrict__ vt2,
                            const float* __restrict__ cemb, float* __restrict__ out,
                            unsigned* __restrict__ doneCtr, int b,
                            float* __restrict__ smem)
{
  float* v1s  = smem;                 // 256
  float* add3 = smem + 256;           // 256
  float* hrow = smem + 512;           // 256
  float* redv = smem + 768;           // 512
  int*   redi = (int*)(smem + 1280);  // 512
  float* sc   = smem + 1792;          // [0]=out2, [1]=r(bits)
  const int tid = threadIdx.x;

  if (tid < 256) v1s[tid] = vt1[tid];
  if (tid == 0) {   // wait until all 512 b12f tiles are published
    int spin = 0;
    while (__hip_atomic_load(doneCtr, __ATOMIC_RELAXED, __HIP_MEMORY_SCOPE_AGENT) < 512u) {
      __builtin_amdgcn_s_sleep(32);
      if (++spin > (1 << 17)) break;  // failsafe
    }
  }
  __syncthreads();

  int bond = 0, last = 0;
  for (int iter = 0; iter < 1024; ++iter) {
    const int t = bond;
    if (tid < 256) {
      const float* hp = ringd + (size_t)t * 256 + tid;   // [t][u] contiguous
      float hv; int spin = 0;
      for (;;) {   // poll decoder h_t (sentinel = not yet produced)
        asm volatile("global_load_dword %0, %1, off sc0 sc1\n\ts_waitcnt vmcnt(0)"
                     : "=v"(hv) : "v"(hp) : "memory");
        if (__float_as_uint(hv) != SENTU) break;
        __builtin_amdgcn_s_sleep(2);
        if (++spin > (1 << 15)) break;  // failsafe
      }
      hrow[tid] = hv;
      redv[tid] = cemb[(t - last) * 256 + tid] * vt2[tid];
    }
    __syncthreads();
    for (int off = 128; off; off >>= 1) {
      if (tid < off) redv[tid] += redv[tid + off];
      __syncthreads();
    }
    if (tid == 0) sc[0] = redv[0];
    __syncthreads();
    if (tid < 256) {
      float a = 0.f;
#pragma unroll 4
      for (int k = 0; k < 256; ++k) a += hrow[k] * W4[k * 256 + tid];
      add3[tid] = a + b3[((b << 10) + t) * 256 + tid];
    }
    __syncthreads();
    const float out2 = sc[0];
    float best = -INFINITY; int bestj = 0x7fffffff;
    for (int j = t + tid; j < 1024; j += 512) {
      const float* row = b12f + (size_t)((b << 10) + j) * 256;
      float sacc = 0.f;
      for (int n = 0; n < 256; n += 16) {
        float4 r0, r1, r2, r3;   // uncached: b12f written sc0 sc1 in-dispatch
        asm volatile("global_load_dwordx4 %0, %4, off sc0 sc1\n\t"
                     "global_load_dwordx4 %1, %4, off offset:16 sc0 sc1\n\t"
                     "global_load_dwordx4 %2, %4, off offset:32 sc0 sc1\n\t"
                     "global_load_dwordx4 %3, %4, off offset:48 sc0 sc1\n\t"
                     "s_waitcnt vmcnt(0)"
                     : "=&v"(r0), "=&v"(r1), "=&v"(r2), "=&v"(r3)
                     : "v"(row + n) : "memory");
        sacc += tanhf(r0.x + add3[n + 0])  * v1s[n + 0];
        sacc += tanhf(r0.y + add3[n + 1])  * v1s[n + 1];
        sacc += tanhf(r0.z + add3[n + 2])  * v1s[n + 2];
        sacc += tanhf(r0.w + add3[n + 3])  * v1s[n + 3];
        sacc += tanhf(r1.x + add3[n + 4])  * v1s[n + 4];
        sacc += tanhf(r1.y + add3[n + 5])  * v1s[n + 5];
        sacc += tanhf(r1.z + add3[n + 6])  * v1s[n + 6];
        sacc += tanhf(r1.w + add3[n + 7])  * v1s[n + 7];
        sacc += tanhf(r2.x + add3[n + 8])  * v1s[n + 8];
        sacc += tanhf(r2.y + add3[n + 9])  * v1s[n + 9];
        sacc += tanhf(r2.z + add3[n + 10]) * v1s[n + 10];
        sacc += tanhf(r2.w + add3[n + 11]) * v1s[n + 11];
        sacc += tanhf(r3.x + add3[n + 12]) * v1s[n + 12];
        sacc += tanhf(r3.y + add3[n + 13]) * v1s[n + 13];
        sacc += tanhf(r3.z + add3[n + 14]) * v1s[n + 14];
        sacc += tanhf(r3.w + add3[n + 15]) * v1s[n + 15];
      }
      const float logit = sacc + out2;
      if (logit > best || (logit == best && j < bestj)) { best = logit; bestj = j; }
    }
    redv[tid] = best; redi[tid] = bestj;
    __syncthreads();
    for (int off = 256; off; off >>= 1) {
      if (tid < off) {
        const float v2 = redv[tid + off]; const int j2 = redi[tid + off];
        if (v2 > redv[tid] || (v2 == redv[tid] && j2 < redi[tid])) {
          redv[tid] = v2; redi[tid] = j2;
        }
      }
      __syncthreads();
    }
    if (tid == 0) { sc[1] = __int_as_float(redi[0]); out[redi[0] * 16 + b] = 1.0f; }
    __syncthreads();
    const int r = __float_as_int(sc[1]);
    if (r == t) break;   // bond stuck -> no further decisions
    last = t; bond = r;
    __syncthreads();
  }
}

// ---------------- Phase 1: 128 chain blocks + 128 persistent workers --------
__global__ __launch_bounds__(512, 1)
void phase1_k(const float* __restrict__ x,
              const float* __restrict__ Wih_f, const float* __restrict__ b_f,
              const float* __restrict__ Whh_f,
              const float* __restrict__ Wih_b, const float* __restrict__ b_b,
              const float* __restrict__ Whh_b,
              const float* __restrict__ W2, const float* __restrict__ W3,
              float* __restrict__ xWf, float* __restrict__ xWb,
              float* __restrict__ b12x, float* __restrict__ b3,
              float* __restrict__ hn, float* __restrict__ hb,
              float* __restrict__ ring, unsigned* __restrict__ tcnt)
{
  __shared__ float smem[3136];
  const int blk = blockIdx.x;
  if (blk < 128) {
    const int dir = blk >> 6, b = (blk >> 2) & 15, seg = blk & 3;
    float* rc = ring + ((size_t)dir * 16 + b) * 1024 * 256;
    const unsigned* xcnt = tcnt + ((dir * 256 + b * 16) << 4);
    lstm_role(dir ? xWb : xWf, dir ? Whh_b : Whh_f, dir ? hb : hn, nullptr,
              rc, xcnt, b, seg * 64, dir, smem);
  } else {
    const int wid = blk - 128;
    for (int tile = wid; tile < 5120; tile += 128) {
      if (tile < 4096) {
        // t-banded xW tiles: fwd ascending, bwd descending
        const int band = tile >> 8, j = tile & 255;
        const int isb = j >> 7, jj = j & 127;
        const int bb = jj >> 3, np = jj & 7;
        const int t64 = isb ? (15 - band) : band;
        const int m0 = (bb << 10) + t64 * 64, n0 = np * 128;
        if (!isb) gemm_tile<0>(x, nullptr, Wih_f, b_f, xWf, 1024, 256, m0, n0, 0, 1, smem);
        else      gemm_tile<0>(x, nullptr, Wih_b, b_b, xWb, 1024, 256, m0, n0, 0, 1, smem);
        asm volatile("s_waitcnt vmcnt(0)" ::: "memory");
        __syncthreads();
        if (threadIdx.x == 0) {
          unsigned* cp = tcnt + ((isb * 256 + bb * 16 + t64) << 4);
          __hip_atomic_fetch_add(cp, 1u, __ATOMIC_RELAXED, __HIP_MEMORY_SCOPE_AGENT);
        }
      } else {
        int k = tile - 4096;          // 0..1023: b12x / b3 interleaved (cached)
        const int which = k & 1; k >>= 1;
        const int m0 = (k >> 1) * 64, n0 = (k & 1) * 128;
        if (which) gemm_tile<0>(x, nullptr, W3, nullptr, b3, 256, 256, m0, n0, 0, 0, smem);
        else       gemm_tile<0>(x, nullptr, W2, nullptr, b12x, 256, 256, m0, n0, 0, 0, smem);
      }
    }
  }
}

// ---------------- Phase 2: 64 decoder + 16 decide + 176 workers -------------
__global__ __launch_bounds__(512, 1)
void phase2_k(const float* __restrict__ x,
              const float* __restrict__ hn, const float* __restrict__ hb,
              const float* __restrict__ dWih, const float* __restrict__ db,
              const float* __restrict__ dWhh, const float* __restrict__ W1,
              float* __restrict__ decIn, float* __restrict__ b12f,
              const float* __restrict__ b3, const float* __restrict__ W4,
              const float* __restrict__ vt1, const float* __restrict__ vt2,
              const float* __restrict__ cemb, float* __restrict__ out,
              float* __restrict__ ring2, unsigned* __restrict__ tcnt,
              unsigned* __restrict__ doneCtr)
{
  __shared__ float smem[3136];
  const int blk = blockIdx.x;
  if (blk < 64) {
    const int b = blk >> 2, seg = blk & 3;
    float* rc = ring2 + (size_t)b * 1024 * 256;
    const unsigned* xcnt = tcnt + ((2 * 256 + b * 16) << 4);
    lstm_role(decIn, dWhh, nullptr, hn, rc, xcnt, b, seg * 64, 0, smem);
  } else if (blk < 80) {
    const int b = blk - 64;
    decide_role(ring2 + (size_t)b * 1024 * 256, b12f, b3, W4, vt1, vt2, cemb,
                out, doneCtr, b, smem);
  } else {
    const int wid = blk - 80;
    for (int tile = wid; tile < 2560; tile += 176) {
      if (tile < 2048) {
        const int band = tile >> 7, j = tile & 127;
        const int bb = j >> 3, np = j & 7;
        const int m0 = (bb << 10) + band * 64, n0 = np * 128;
        gemm_tile<1>(x, hn, dWih, db, decIn, 1024, 512, m0, n0, 0, 1, smem);
        asm volatile("s_waitcnt vmcnt(0)" ::: "memory");
        __syncthreads();
        if (threadIdx.x == 0) {
          unsigned* cp = tcnt + ((2 * 256 + bb * 16 + band) << 4);
          __hip_atomic_fetch_add(cp, 1u, __ATOMIC_RELAXED, __HIP_MEMORY_SCOPE_AGENT);
        }
      } else {
        const int k = tile - 2048;    // b12f = b12x + [hn,hb]@W1 (in place)
        const int m0 = (k >> 1) * 64, n0 = (k & 1) * 128;
        gemm_tile<2>(hn, hb, W1, nullptr, b12f, 256, 512, m0, n0, 1, 1, smem);
        asm volatile("s_waitcnt vmcnt(0)" ::: "memory");
        __syncthreads();
        if (threadIdx.x == 0)
          __hip_atomic_fetch_add(doneCtr, 1u, __ATOMIC_RELEASE, __HIP_MEMORY_SCOPE_AGENT);
      }
    }
  }
}

// ---------------------------------------------------------------------------
extern "C" void kernel_launch(void* const* d_in, const int* in_sizes, int n_in,
                              void* d_out, int out_size, void* d_ws, size_t ws_size,
                              hipStream_t stream)
{
  const float* x     = (const float*)d_in[0];
  const float* Wih_f = (const float*)d_in[1];
  const float* Whh_f = (const float*)d_in[2];
  const float* b_f   = (const float*)d_in[3];
  const float* Wih_b = (const float*)d_in[4];
  const float* Whh_b = (const float*)d_in[5];
  const float* b_b   = (const float*)d_in[6];
  const float* dWih  = (const float*)d_in[7];
  const float* dWhh  = (const float*)d_in[8];
  const float* db    = (const float*)d_in[9];
  const float* W1    = (const float*)d_in[10];
  const float* W2    = (const float*)d_in[11];
  const float* W3    = (const float*)d_in[12];
  const float* W4    = (const float*)d_in[13];
  const float* vt1   = (const float*)d_in[14];
  const float* vt2   = (const float*)d_in[15];
  const float* cemb  = (const float*)d_in[16];
  float* out = (float*)d_out;

  char* ws = (char*)d_ws;
  float*    xWf  = (float*)(ws);                        // 64 MB (aliased decIn)
  float*    xWb  = (float*)(ws + (size_t)(64u << 20));  // 64 MB
  float*    hn   = (float*)(ws + (size_t)(128u << 20)); // 16 MB
  float*    hb   = (float*)(ws + (size_t)(144u << 20)); // 16 MB
  float*    b12  = (float*)(ws + (size_t)(160u << 20)); // 16 MB (b12x -> b12f)
  float*    b3   = (float*)(ws + (size_t)(176u << 20)); // 16 MB
  float*    ring = (float*)(ws + (size_t)(192u << 20)); // 48 MB: encF, encB, dec
  unsigned* ctr  = (unsigned*)(ws + (size_t)(240u << 20));        // doneCtr
  unsigned* tcnt = (unsigned*)(ws + (size_t)(240u << 20) + 4096); // 768 ctrs x 64B
  float* decIn = xWf;
  float* ring2 = ring + (size_t)2 * 16 * 1024 * 256;    // decoder rings (16 MB)

  // Rings need sentinel poison; counters zeroed (xW buffers counter-gated).
  (void)hipMemsetAsync(ring, 0xAA, (size_t)3 * 16 * 1024 * 256 * sizeof(float), stream);
  (void)hipMemsetAsync(ctr, 0, 4096 + 768 * 64, stream);
  (void)hipMemsetAsync(out, 0, (size_t)out_size * sizeof(float), stream);

  phase1_k<<<256, 512, 0, stream>>>(x, Wih_f, b_f, Whh_f, Wih_b, b_b, Whh_b,
                                    W2, W3, xWf, xWb, b12, b3, hn, hb, ring, tcnt);
  phase2_k<<<256, 512, 0, stream>>>(x, hn, hb, dWih, db, dWhh, W1,
                                    decIn, b12, b3, W4, vt1, vt2, cemb, out,
                                    ring2, tcnt, ctr);
}